// Round 2
// baseline (2712.634 us; speedup 1.0000x reference)
//
#include <hip/hip_runtime.h>
#include <hip/hip_bf16.h>

constexpr int kNUser = 100000;
constexpr int kNItem = 50000;
constexpr int kN     = 150000;
constexpr int kEmb   = 64;
constexpr int kFeat  = 384;
constexpr int kNnz   = 2400000;
constexpr float kEps = 1e-8f;

// ---- prompt_embd = sum over 8 prompt rows -> f_ps[64] ----
__global__ void prompt_sum_k(const float* __restrict__ p, float* __restrict__ out) {
    int d = threadIdx.x;  // 64 threads
    float s = 0.f;
#pragma unroll
    for (int i = 0; i < 8; ++i) s += p[i * kEmb + d];
    out[d] = s;
}

// ---- ego[:N_USER] = user_fea + prompt ----
__global__ void user_ego_k(const float* __restrict__ uf, const float* __restrict__ ps,
                           float* __restrict__ ego) {
    int i = blockIdx.x * blockDim.x + threadIdx.x;
    if (i >= kNUser * kEmb) return;
    ego[i] = uf[i] + ps[i & 63];
}

// ---- ego[N_USER:] = tanh(item_fea @ mlp_w + mlp_b) ----
// one wave per item row; lane = output column
__global__ void item_ego_k(const float* __restrict__ itf, const float* __restrict__ w,
                           const float* __restrict__ b, float* __restrict__ ego) {
    int wid  = threadIdx.x >> 6;
    int lane = threadIdx.x & 63;
    int row  = blockIdx.x * 4 + wid;
    if (row >= kNItem) return;
    const float* arow = itf + (size_t)row * kFeat;
    float acc = 0.f;
#pragma unroll 4
    for (int k = 0; k < kFeat; ++k)
        acc += arow[k] * w[k * kEmb + lane];  // w load coalesced across lanes
    acc += b[lane];
    ego[(size_t)(kNUser + row) * kEmb + lane] = tanhf(acc);
}

// ---- ego_norm per row; init x = ego, acc = ego (acc lives in d_out) ----
__global__ void norm_init_k(const float* __restrict__ ego, float* __restrict__ nrm,
                            float* __restrict__ x, float* __restrict__ acc) {
    int wid  = threadIdx.x >> 6;
    int lane = threadIdx.x & 63;
    int row  = blockIdx.x * 4 + wid;
    if (row >= kN) return;
    size_t idx = (size_t)row * kEmb + lane;
    float e = ego[idx];
    x[idx]   = e;
    acc[idx] = e;
    float s = e * e;
#pragma unroll
    for (int o = 32; o >= 1; o >>= 1) s += __shfl_xor(s, o, 64);
    if (lane == 0) nrm[row] = sqrtf(s);
}

// ---- y[rows[e]] += vals[e] * x[cols[e]] ; one wave per edge, lane = dim ----
__global__ void spmm_k(const int* __restrict__ rows, const int* __restrict__ cols,
                       const float* __restrict__ vals, const float* __restrict__ x,
                       float* __restrict__ y) {
    long long t = (long long)blockIdx.x * blockDim.x + threadIdx.x;
    int e = (int)(t >> 6);
    if (e >= kNnz) return;
    int lane = threadIdx.x & 63;
    int r = rows[e];               // wave-uniform
    int c = cols[e];               // wave-uniform
    float v = vals[e];             // wave-uniform
    atomicAdd(y + (size_t)r * kEmb + lane, v * x[(size_t)c * kEmb + lane]);
}

// ---- per-row cosine reweight: x = w*y ; acc += x ----
__global__ void weight_k(const float* __restrict__ ego, const float* __restrict__ nrm,
                         const float* __restrict__ y, float* __restrict__ x,
                         float* __restrict__ acc) {
    int wid  = threadIdx.x >> 6;
    int lane = threadIdx.x & 63;
    int row  = blockIdx.x * 4 + wid;
    if (row >= kN) return;
    size_t idx = (size_t)row * kEmb + lane;
    float yv = y[idx];
    float ev = ego[idx];
    float d = yv * ev;
    float n = yv * yv;
#pragma unroll
    for (int o = 32; o >= 1; o >>= 1) {
        d += __shfl_xor(d, o, 64);
        n += __shfl_xor(n, o, 64);
    }
    float w  = d / fmaxf(sqrtf(n) * nrm[row], kEps);
    float xw = w * yv;
    x[idx] = xw;
    acc[idx] += xw;
}

extern "C" void kernel_launch(void* const* d_in, const int* in_sizes, int n_in,
                              void* d_out, int out_size, void* d_ws, size_t ws_size,
                              hipStream_t stream) {
    const float* user_fea = (const float*)d_in[0];
    const float* item_fea = (const float*)d_in[1];
    const float* prompt   = (const float*)d_in[2];
    const float* mlp_w    = (const float*)d_in[3];
    const float* mlp_b    = (const float*)d_in[4];
    const int*   adj_rows = (const int*)d_in[5];
    const int*   adj_cols = (const int*)d_in[6];
    const float* adj_vals = (const float*)d_in[7];
    float* acc = (float*)d_out;   // running layer sum accumulates in-place in d_out

    const size_t NE = (size_t)kN * kEmb;  // 9.6M floats
    float* ws    = (float*)d_ws;
    float* f_ego = ws;            // [N, 64] fp32
    float* f_x   = f_ego + NE;    // [N, 64] fp32 (current layer input)
    float* f_y   = f_x + NE;      // [N, 64] fp32 (spmm output)
    float* f_nrm = f_y + NE;      // [N] fp32
    float* f_ps  = f_nrm + kN;    // [64] fp32

    prompt_sum_k<<<1, 64, 0, stream>>>(prompt, f_ps);
    user_ego_k<<<(kNUser * kEmb + 255) / 256, 256, 0, stream>>>(user_fea, f_ps, f_ego);
    item_ego_k<<<(kNItem + 3) / 4, 256, 0, stream>>>(item_fea, mlp_w, mlp_b, f_ego);
    norm_init_k<<<(kN + 3) / 4, 256, 0, stream>>>(f_ego, f_nrm, f_x, acc);

    for (int l = 0; l < 4; ++l) {
        hipMemsetAsync(f_y, 0, NE * sizeof(float), stream);
        spmm_k<<<(int)(((long long)kNnz * 64 + 255) / 256), 256, 0, stream>>>(
            adj_rows, adj_cols, adj_vals, f_x, f_y);
        weight_k<<<(kN + 3) / 4, 256, 0, stream>>>(f_ego, f_nrm, f_y, f_x, acc);
    }
}

// Round 3
// 1233.178 us; speedup vs baseline: 2.1997x; 2.1997x over previous
//
#include <hip/hip_runtime.h>

constexpr int kNUser = 100000;
constexpr int kNItem = 50000;
constexpr int kN     = 150000;
constexpr int kEmb   = 64;
constexpr int kFeat  = 384;
constexpr int kNnz   = 2400000;
constexpr float kEps = 1e-8f;

constexpr int kChunk = 1024;                       // elements per scan block
constexpr int kNB    = (kN + kChunk - 1) / kChunk; // 147 scan blocks

// ================= shared init kernels =================

__global__ void prompt_sum_k(const float* __restrict__ p, float* __restrict__ out) {
    int d = threadIdx.x;  // 64 threads
    float s = 0.f;
#pragma unroll
    for (int i = 0; i < 8; ++i) s += p[i * kEmb + d];
    out[d] = s;
}

__global__ void user_ego_k(const float* __restrict__ uf, const float* __restrict__ ps,
                           float* __restrict__ ego) {
    int i = blockIdx.x * blockDim.x + threadIdx.x;
    if (i >= kNUser * kEmb) return;
    ego[i] = uf[i] + ps[i & 63];
}

__global__ void item_ego_k(const float* __restrict__ itf, const float* __restrict__ w,
                           const float* __restrict__ b, float* __restrict__ ego) {
    int wid  = threadIdx.x >> 6;
    int lane = threadIdx.x & 63;
    int row  = blockIdx.x * 4 + wid;
    if (row >= kNItem) return;
    const float* arow = itf + (size_t)row * kFeat;
    float acc = 0.f;
#pragma unroll 4
    for (int k = 0; k < kFeat; ++k)
        acc += arow[k] * w[k * kEmb + lane];
    acc += b[lane];
    ego[(size_t)(kNUser + row) * kEmb + lane] = tanhf(acc);
}

// nrm + acc init (CSR path: layer 0 reads ego directly, no x copy needed)
__global__ void norm_init_csr_k(const float* __restrict__ ego, float* __restrict__ nrm,
                                float* __restrict__ acc) {
    int wid  = threadIdx.x >> 6;
    int lane = threadIdx.x & 63;
    int row  = blockIdx.x * 4 + wid;
    if (row >= kN) return;
    size_t idx = (size_t)row * kEmb + lane;
    float e = ego[idx];
    acc[idx] = e;
    float s = e * e;
#pragma unroll
    for (int o = 32; o >= 1; o >>= 1) s += __shfl_xor(s, o, 64);
    if (lane == 0) nrm[row] = sqrtf(s);
}

// ================= CSR build =================

__global__ void hist_k(const int* __restrict__ rows, int* __restrict__ cnt) {
    int e = blockIdx.x * blockDim.x + threadIdx.x;
    if (e < kNnz) atomicAdd(&cnt[rows[e]], 1);
}

// per-chunk exclusive scan; chunk = 1024 elems, 256 threads x 4 elems
__global__ void scan1_k(const int* __restrict__ cnt, int* __restrict__ excl_out,
                        int* __restrict__ blk_sum) {
    __shared__ int sd[256];
    int b = blockIdx.x, t = threadIdx.x;
    int base = b * kChunk + t * 4;
    int c0 = (base + 0 < kN) ? cnt[base + 0] : 0;
    int c1 = (base + 1 < kN) ? cnt[base + 1] : 0;
    int c2 = (base + 2 < kN) ? cnt[base + 2] : 0;
    int c3 = (base + 3 < kN) ? cnt[base + 3] : 0;
    int tsum = c0 + c1 + c2 + c3;
    sd[t] = tsum;
    __syncthreads();
#pragma unroll
    for (int off = 1; off < 256; off <<= 1) {
        int v = (t >= off) ? sd[t - off] : 0;
        __syncthreads();
        sd[t] += v;
        __syncthreads();
    }
    int excl = sd[t] - tsum;
    if (t == 255) blk_sum[b] = sd[255];
    int run = excl;
    if (base + 0 < kN) { excl_out[base + 0] = run; run += c0; }
    if (base + 1 < kN) { excl_out[base + 1] = run; run += c1; }
    if (base + 2 < kN) { excl_out[base + 2] = run; run += c2; }
    if (base + 3 < kN) { excl_out[base + 3] = run; run += c3; }
}

// single-block exclusive scan of the 147 block sums
__global__ void scan2_k(const int* __restrict__ blk_sum, int* __restrict__ blk_off) {
    __shared__ int sd[256];
    int t = threadIdx.x;
    int v = (t < kNB) ? blk_sum[t] : 0;
    sd[t] = v;
    __syncthreads();
#pragma unroll
    for (int off = 1; off < 256; off <<= 1) {
        int u = (t >= off) ? sd[t - off] : 0;
        __syncthreads();
        sd[t] += u;
        __syncthreads();
    }
    if (t < kNB) blk_off[t] = sd[t] - v;
}

// add block offsets; produce row_ptr and the mutable cursor copy row_fill
__global__ void scan3_k(int* __restrict__ rp, int* __restrict__ rf,
                        const int* __restrict__ blk_off) {
    int b = blockIdx.x, t = threadIdx.x;
    int base = b * kChunk + t * 4;
    int o = blk_off[b];
#pragma unroll
    for (int k = 0; k < 4; ++k) {
        int i = base + k;
        if (i < kN) { int v = rp[i] + o; rp[i] = v; rf[i] = v; }
    }
    if (b == 0 && t == 0) rp[kN] = kNnz;
}

__global__ void scatter_k(const int* __restrict__ rows, const int* __restrict__ cols,
                          const float* __restrict__ vals, int* __restrict__ rf,
                          int2* __restrict__ csr) {
    int e = blockIdx.x * blockDim.x + threadIdx.x;
    if (e >= kNnz) return;
    int r = rows[e];
    int pos = atomicAdd(&rf[r], 1);
    csr[pos] = make_int2(cols[e], __float_as_int(vals[e]));
}

// ============ fused layer: pull-SpMM + cosine reweight + acc ============
// one wave per row; lane = embedding dim
__global__ void layer_k(const int* __restrict__ rp, const int2* __restrict__ csr,
                        const float* __restrict__ ego, const float* __restrict__ nrm,
                        const float* __restrict__ xin, float* __restrict__ xout,
                        float* __restrict__ acc) {
    int wid  = threadIdx.x >> 6;
    int lane = threadIdx.x & 63;
    int row  = blockIdx.x * 4 + wid;
    if (row >= kN) return;
    int p0 = rp[row];
    int p1 = rp[row + 1];
    float s = 0.f;
    int j = p0;
    for (; j + 4 <= p1; j += 4) {   // unroll x4 for gather ILP
        int2 e0 = csr[j], e1 = csr[j + 1], e2 = csr[j + 2], e3 = csr[j + 3];
        float a0 = xin[(size_t)e0.x * kEmb + lane];
        float a1 = xin[(size_t)e1.x * kEmb + lane];
        float a2 = xin[(size_t)e2.x * kEmb + lane];
        float a3 = xin[(size_t)e3.x * kEmb + lane];
        s = fmaf(__int_as_float(e0.y), a0, s);
        s = fmaf(__int_as_float(e1.y), a1, s);
        s = fmaf(__int_as_float(e2.y), a2, s);
        s = fmaf(__int_as_float(e3.y), a3, s);
    }
    for (; j < p1; ++j) {
        int2 e = csr[j];
        s = fmaf(__int_as_float(e.y), xin[(size_t)e.x * kEmb + lane], s);
    }
    size_t idx = (size_t)row * kEmb + lane;
    float ev = ego[idx];
    float d = s * ev;
    float n = s * s;
#pragma unroll
    for (int o = 32; o >= 1; o >>= 1) {
        d += __shfl_xor(d, o, 64);
        n += __shfl_xor(n, o, 64);
    }
    float w  = d / fmaxf(sqrtf(n) * nrm[row], kEps);
    float xw = w * s;
    xout[idx] = xw;
    acc[idx] += xw;
}

// ================= fallback (R2 path) kernels =================

__global__ void norm_init_full_k(const float* __restrict__ ego, float* __restrict__ nrm,
                                 float* __restrict__ x, float* __restrict__ acc) {
    int wid  = threadIdx.x >> 6;
    int lane = threadIdx.x & 63;
    int row  = blockIdx.x * 4 + wid;
    if (row >= kN) return;
    size_t idx = (size_t)row * kEmb + lane;
    float e = ego[idx];
    x[idx]   = e;
    acc[idx] = e;
    float s = e * e;
#pragma unroll
    for (int o = 32; o >= 1; o >>= 1) s += __shfl_xor(s, o, 64);
    if (lane == 0) nrm[row] = sqrtf(s);
}

__global__ void spmm_k(const int* __restrict__ rows, const int* __restrict__ cols,
                       const float* __restrict__ vals, const float* __restrict__ x,
                       float* __restrict__ y) {
    long long t = (long long)blockIdx.x * blockDim.x + threadIdx.x;
    int e = (int)(t >> 6);
    if (e >= kNnz) return;
    int lane = threadIdx.x & 63;
    atomicAdd(y + (size_t)rows[e] * kEmb + lane, vals[e] * x[(size_t)cols[e] * kEmb + lane]);
}

__global__ void weight_k(const float* __restrict__ ego, const float* __restrict__ nrm,
                         const float* __restrict__ y, float* __restrict__ x,
                         float* __restrict__ acc) {
    int wid  = threadIdx.x >> 6;
    int lane = threadIdx.x & 63;
    int row  = blockIdx.x * 4 + wid;
    if (row >= kN) return;
    size_t idx = (size_t)row * kEmb + lane;
    float yv = y[idx];
    float ev = ego[idx];
    float d = yv * ev;
    float n = yv * yv;
#pragma unroll
    for (int o = 32; o >= 1; o >>= 1) {
        d += __shfl_xor(d, o, 64);
        n += __shfl_xor(n, o, 64);
    }
    float w  = d / fmaxf(sqrtf(n) * nrm[row], kEps);
    float xw = w * yv;
    x[idx] = xw;
    acc[idx] += xw;
}

// ================= launch =================

extern "C" void kernel_launch(void* const* d_in, const int* in_sizes, int n_in,
                              void* d_out, int out_size, void* d_ws, size_t ws_size,
                              hipStream_t stream) {
    const float* user_fea = (const float*)d_in[0];
    const float* item_fea = (const float*)d_in[1];
    const float* prompt   = (const float*)d_in[2];
    const float* mlp_w    = (const float*)d_in[3];
    const float* mlp_b    = (const float*)d_in[4];
    const int*   adj_rows = (const int*)d_in[5];
    const int*   adj_cols = (const int*)d_in[6];
    const float* adj_vals = (const float*)d_in[7];
    float* acc = (float*)d_out;   // running layer sum accumulates in-place in d_out

    const size_t NE = (size_t)kN * kEmb;  // 9.6M
    float* ws = (float*)d_ws;

    // ---- CSR-path workspace layout (4-byte units) ----
    size_t off = 0;
    float* f_ego = ws + off; off += NE;
    float* f_xa  = ws + off; off += NE;
    float* f_xb  = ws + off; off += NE;
    float* f_nrm = ws + off; off += kN;
    float* f_ps  = ws + off; off += 64;
    int* row_cnt  = (int*)(ws + off); off += kN;
    int* row_ptr  = (int*)(ws + off); off += kN + 1;
    int* row_fill = (int*)(ws + off); off += kN;
    int* blk_sum  = (int*)(ws + off); off += kNB;
    int* blk_off  = (int*)(ws + off); off += kNB;
    off = (off + 1) & ~(size_t)1;                   // 8B-align csr
    int2* csr = (int2*)(ws + off); off += (size_t)kNnz * 2;
    const bool use_csr = ws_size >= off * 4;

    // ---- common init ----
    prompt_sum_k<<<1, 64, 0, stream>>>(prompt, f_ps);
    user_ego_k<<<(kNUser * kEmb + 255) / 256, 256, 0, stream>>>(user_fea, f_ps, f_ego);
    item_ego_k<<<(kNItem + 3) / 4, 256, 0, stream>>>(item_fea, mlp_w, mlp_b, f_ego);

    if (use_csr) {
        // ---- build CSR (amortized over 4 layers) ----
        hipMemsetAsync(row_cnt, 0, kN * sizeof(int), stream);
        hist_k<<<(kNnz + 255) / 256, 256, 0, stream>>>(adj_rows, row_cnt);
        scan1_k<<<kNB, 256, 0, stream>>>(row_cnt, row_ptr, blk_sum);
        scan2_k<<<1, 256, 0, stream>>>(blk_sum, blk_off);
        scan3_k<<<kNB, 256, 0, stream>>>(row_ptr, row_fill, blk_off);
        scatter_k<<<(kNnz + 255) / 256, 256, 0, stream>>>(adj_rows, adj_cols, adj_vals,
                                                          row_fill, csr);

        norm_init_csr_k<<<(kN + 3) / 4, 256, 0, stream>>>(f_ego, f_nrm, acc);

        // ---- 4 fused layers: ego -> xa -> xb -> xa -> xb ----
        const float* xin = f_ego;
        float* xout = f_xa;
        for (int l = 0; l < 4; ++l) {
            layer_k<<<(kN + 3) / 4, 256, 0, stream>>>(row_ptr, csr, f_ego, f_nrm,
                                                      xin, xout, acc);
            xin  = xout;
            xout = (xout == f_xa) ? f_xb : f_xa;
        }
    } else {
        // ---- fallback: R2 atomic path (ws layout fits in 3 big buffers) ----
        float* f_x = f_xa;
        float* f_y = f_xb;
        norm_init_full_k<<<(kN + 3) / 4, 256, 0, stream>>>(f_ego, f_nrm, f_x, acc);
        for (int l = 0; l < 4; ++l) {
            hipMemsetAsync(f_y, 0, NE * sizeof(float), stream);
            spmm_k<<<(int)(((long long)kNnz * 64 + 255) / 256), 256, 0, stream>>>(
                adj_rows, adj_cols, adj_vals, f_x, f_y);
            weight_k<<<(kN + 3) / 4, 256, 0, stream>>>(f_ego, f_nrm, f_y, f_x, acc);
        }
    }
}

// Round 4
// 1211.330 us; speedup vs baseline: 2.2394x; 1.0180x over previous
//
#include <hip/hip_runtime.h>

constexpr int kNUser = 100000;
constexpr int kNItem = 50000;
constexpr int kN     = 150000;
constexpr int kEmb   = 64;
constexpr int kFeat  = 384;
constexpr int kNnz   = 2400000;
constexpr float kEps = 1e-8f;

constexpr int kChunk = 1024;                       // elements per scan block
constexpr int kNB    = (kN + kChunk - 1) / kChunk; // 147 scan blocks

// ================= shared init kernels =================

__global__ void prompt_sum_k(const float* __restrict__ p, float* __restrict__ out) {
    int d = threadIdx.x;  // 64 threads
    float s = 0.f;
#pragma unroll
    for (int i = 0; i < 8; ++i) s += p[i * kEmb + d];
    out[d] = s;
}

__global__ void user_ego_k(const float* __restrict__ uf, const float* __restrict__ ps,
                           float* __restrict__ ego) {
    int i = blockIdx.x * blockDim.x + threadIdx.x;
    if (i >= kNUser * kEmb) return;
    ego[i] = uf[i] + ps[i & 63];
}

// ---- item MLP: 16 rows per wave, lane = out col; w chunk in registers ----
// w re-read per 16 rows (not per row): L2 traffic 4.9GB -> 307MB.
constexpr int kRW = 16;
__global__ void item_ego_k(const float* __restrict__ itf, const float* __restrict__ w,
                           const float* __restrict__ b, float* __restrict__ ego) {
    int wid  = threadIdx.x >> 6;
    int lane = threadIdx.x & 63;
    int r0   = (blockIdx.x * 4 + wid) * kRW;
    if (r0 >= kNItem) return;
    float acc[kRW];
#pragma unroll
    for (int r = 0; r < kRW; ++r) acc[r] = 0.f;

    for (int kc = 0; kc < kFeat; kc += 32) {
        float wreg[32];
#pragma unroll
        for (int k = 0; k < 32; ++k) wreg[k] = w[(kc + k) * kEmb + lane];  // coalesced
#pragma unroll
        for (int r = 0; r < kRW; ++r) {
            const float4* ar = (const float4*)(itf + (size_t)(r0 + r) * kFeat + kc);
#pragma unroll
            for (int q = 0; q < 8; ++q) {            // wave-uniform broadcast loads
                float4 a = ar[q];
                acc[r] = fmaf(a.x, wreg[q * 4 + 0], acc[r]);
                acc[r] = fmaf(a.y, wreg[q * 4 + 1], acc[r]);
                acc[r] = fmaf(a.z, wreg[q * 4 + 2], acc[r]);
                acc[r] = fmaf(a.w, wreg[q * 4 + 3], acc[r]);
            }
        }
    }
    float bv = b[lane];
#pragma unroll
    for (int r = 0; r < kRW; ++r) {
        if (r0 + r < kNItem)
            ego[(size_t)(kNUser + r0 + r) * kEmb + lane] = tanhf(acc[r] + bv);
    }
}

// nrm + acc init (CSR path: layer 0 reads ego directly, no x copy needed)
__global__ void norm_init_csr_k(const float* __restrict__ ego, float* __restrict__ nrm,
                                float* __restrict__ acc) {
    int wid  = threadIdx.x >> 6;
    int lane = threadIdx.x & 63;
    int row  = blockIdx.x * 4 + wid;
    if (row >= kN) return;
    size_t idx = (size_t)row * kEmb + lane;
    float e = ego[idx];
    acc[idx] = e;
    float s = e * e;
#pragma unroll
    for (int o = 32; o >= 1; o >>= 1) s += __shfl_xor(s, o, 64);
    if (lane == 0) nrm[row] = sqrtf(s);
}

// ================= CSR build =================

__global__ void hist_k(const int* __restrict__ rows, int* __restrict__ cnt) {
    int e = blockIdx.x * blockDim.x + threadIdx.x;
    if (e < kNnz) atomicAdd(&cnt[rows[e]], 1);
}

__global__ void scan1_k(const int* __restrict__ cnt, int* __restrict__ excl_out,
                        int* __restrict__ blk_sum) {
    __shared__ int sd[256];
    int b = blockIdx.x, t = threadIdx.x;
    int base = b * kChunk + t * 4;
    int c0 = (base + 0 < kN) ? cnt[base + 0] : 0;
    int c1 = (base + 1 < kN) ? cnt[base + 1] : 0;
    int c2 = (base + 2 < kN) ? cnt[base + 2] : 0;
    int c3 = (base + 3 < kN) ? cnt[base + 3] : 0;
    int tsum = c0 + c1 + c2 + c3;
    sd[t] = tsum;
    __syncthreads();
#pragma unroll
    for (int off = 1; off < 256; off <<= 1) {
        int v = (t >= off) ? sd[t - off] : 0;
        __syncthreads();
        sd[t] += v;
        __syncthreads();
    }
    int excl = sd[t] - tsum;
    if (t == 255) blk_sum[b] = sd[255];
    int run = excl;
    if (base + 0 < kN) { excl_out[base + 0] = run; run += c0; }
    if (base + 1 < kN) { excl_out[base + 1] = run; run += c1; }
    if (base + 2 < kN) { excl_out[base + 2] = run; run += c2; }
    if (base + 3 < kN) { excl_out[base + 3] = run; run += c3; }
}

__global__ void scan2_k(const int* __restrict__ blk_sum, int* __restrict__ blk_off) {
    __shared__ int sd[256];
    int t = threadIdx.x;
    int v = (t < kNB) ? blk_sum[t] : 0;
    sd[t] = v;
    __syncthreads();
#pragma unroll
    for (int off = 1; off < 256; off <<= 1) {
        int u = (t >= off) ? sd[t - off] : 0;
        __syncthreads();
        sd[t] += u;
        __syncthreads();
    }
    if (t < kNB) blk_off[t] = sd[t] - v;
}

__global__ void scan3_k(int* __restrict__ rp, int* __restrict__ rf,
                        const int* __restrict__ blk_off) {
    int b = blockIdx.x, t = threadIdx.x;
    int base = b * kChunk + t * 4;
    int o = blk_off[b];
#pragma unroll
    for (int k = 0; k < 4; ++k) {
        int i = base + k;
        if (i < kN) { int v = rp[i] + o; rp[i] = v; rf[i] = v; }
    }
    if (b == 0 && t == 0) rp[kN] = kNnz;
}

__global__ void scatter_k(const int* __restrict__ rows, const int* __restrict__ cols,
                          const float* __restrict__ vals, int* __restrict__ rf,
                          int2* __restrict__ csr) {
    int e = blockIdx.x * blockDim.x + threadIdx.x;
    if (e >= kNnz) return;
    int r = rows[e];
    int pos = atomicAdd(&rf[r], 1);
    csr[pos] = make_int2(cols[e], __float_as_int(vals[e]));
}

// ============ fused layer: pull-SpMM + cosine reweight + acc ============
// one wave per row; lane = embedding dim; gather unrolled x8 for MLP latency hiding
__global__ void layer_k(const int* __restrict__ rp, const int2* __restrict__ csr,
                        const float* __restrict__ ego, const float* __restrict__ nrm,
                        const float* __restrict__ xin, float* __restrict__ xout,
                        float* __restrict__ acc) {
    int wid  = threadIdx.x >> 6;
    int lane = threadIdx.x & 63;
    int row  = blockIdx.x * 4 + wid;
    if (row >= kN) return;
    int p0 = rp[row];
    int p1 = rp[row + 1];
    float s = 0.f;
    int j = p0;
    for (; j + 8 <= p1; j += 8) {
        int2 e[8];
        float a[8];
#pragma unroll
        for (int q = 0; q < 8; ++q) e[q] = csr[j + q];
#pragma unroll
        for (int q = 0; q < 8; ++q) a[q] = xin[(size_t)e[q].x * kEmb + lane];
#pragma unroll
        for (int q = 0; q < 8; ++q) s = fmaf(__int_as_float(e[q].y), a[q], s);
    }
    for (; j + 4 <= p1; j += 4) {
        int2 e0 = csr[j], e1 = csr[j + 1], e2 = csr[j + 2], e3 = csr[j + 3];
        float a0 = xin[(size_t)e0.x * kEmb + lane];
        float a1 = xin[(size_t)e1.x * kEmb + lane];
        float a2 = xin[(size_t)e2.x * kEmb + lane];
        float a3 = xin[(size_t)e3.x * kEmb + lane];
        s = fmaf(__int_as_float(e0.y), a0, s);
        s = fmaf(__int_as_float(e1.y), a1, s);
        s = fmaf(__int_as_float(e2.y), a2, s);
        s = fmaf(__int_as_float(e3.y), a3, s);
    }
    for (; j < p1; ++j) {
        int2 e = csr[j];
        s = fmaf(__int_as_float(e.y), xin[(size_t)e.x * kEmb + lane], s);
    }
    size_t idx = (size_t)row * kEmb + lane;
    float ev = ego[idx];
    float d = s * ev;
    float n = s * s;
#pragma unroll
    for (int o = 32; o >= 1; o >>= 1) {
        d += __shfl_xor(d, o, 64);
        n += __shfl_xor(n, o, 64);
    }
    float w  = d / fmaxf(sqrtf(n) * nrm[row], kEps);
    float xw = w * s;
    xout[idx] = xw;
    acc[idx] += xw;
}

// ================= fallback (atomic) kernels =================

__global__ void norm_init_full_k(const float* __restrict__ ego, float* __restrict__ nrm,
                                 float* __restrict__ x, float* __restrict__ acc) {
    int wid  = threadIdx.x >> 6;
    int lane = threadIdx.x & 63;
    int row  = blockIdx.x * 4 + wid;
    if (row >= kN) return;
    size_t idx = (size_t)row * kEmb + lane;
    float e = ego[idx];
    x[idx]   = e;
    acc[idx] = e;
    float s = e * e;
#pragma unroll
    for (int o = 32; o >= 1; o >>= 1) s += __shfl_xor(s, o, 64);
    if (lane == 0) nrm[row] = sqrtf(s);
}

__global__ void spmm_k(const int* __restrict__ rows, const int* __restrict__ cols,
                       const float* __restrict__ vals, const float* __restrict__ x,
                       float* __restrict__ y) {
    long long t = (long long)blockIdx.x * blockDim.x + threadIdx.x;
    int e = (int)(t >> 6);
    if (e >= kNnz) return;
    int lane = threadIdx.x & 63;
    atomicAdd(y + (size_t)rows[e] * kEmb + lane, vals[e] * x[(size_t)cols[e] * kEmb + lane]);
}

__global__ void weight_k(const float* __restrict__ ego, const float* __restrict__ nrm,
                         const float* __restrict__ y, float* __restrict__ x,
                         float* __restrict__ acc) {
    int wid  = threadIdx.x >> 6;
    int lane = threadIdx.x & 63;
    int row  = blockIdx.x * 4 + wid;
    if (row >= kN) return;
    size_t idx = (size_t)row * kEmb + lane;
    float yv = y[idx];
    float ev = ego[idx];
    float d = yv * ev;
    float n = yv * yv;
#pragma unroll
    for (int o = 32; o >= 1; o >>= 1) {
        d += __shfl_xor(d, o, 64);
        n += __shfl_xor(n, o, 64);
    }
    float w  = d / fmaxf(sqrtf(n) * nrm[row], kEps);
    float xw = w * yv;
    x[idx] = xw;
    acc[idx] += xw;
}

// ================= launch =================

extern "C" void kernel_launch(void* const* d_in, const int* in_sizes, int n_in,
                              void* d_out, int out_size, void* d_ws, size_t ws_size,
                              hipStream_t stream) {
    const float* user_fea = (const float*)d_in[0];
    const float* item_fea = (const float*)d_in[1];
    const float* prompt   = (const float*)d_in[2];
    const float* mlp_w    = (const float*)d_in[3];
    const float* mlp_b    = (const float*)d_in[4];
    const int*   adj_rows = (const int*)d_in[5];
    const int*   adj_cols = (const int*)d_in[6];
    const float* adj_vals = (const float*)d_in[7];
    float* acc = (float*)d_out;   // running layer sum accumulates in-place in d_out

    const size_t NE = (size_t)kN * kEmb;  // 9.6M
    float* ws = (float*)d_ws;

    // ---- CSR-path workspace layout (4-byte units) ----
    size_t off = 0;
    float* f_ego = ws + off; off += NE;
    float* f_xa  = ws + off; off += NE;
    float* f_xb  = ws + off; off += NE;
    float* f_nrm = ws + off; off += kN;
    float* f_ps  = ws + off; off += 64;
    int* row_cnt  = (int*)(ws + off); off += kN;
    int* row_ptr  = (int*)(ws + off); off += kN + 1;
    int* row_fill = (int*)(ws + off); off += kN;
    int* blk_sum  = (int*)(ws + off); off += kNB;
    int* blk_off  = (int*)(ws + off); off += kNB;
    off = (off + 1) & ~(size_t)1;                   // 8B-align csr
    int2* csr = (int2*)(ws + off); off += (size_t)kNnz * 2;
    const bool use_csr = ws_size >= off * 4;

    // ---- common init ----
    prompt_sum_k<<<1, 64, 0, stream>>>(prompt, f_ps);
    user_ego_k<<<(kNUser * kEmb + 255) / 256, 256, 0, stream>>>(user_fea, f_ps, f_ego);
    item_ego_k<<<(kNItem + 4 * kRW - 1) / (4 * kRW), 256, 0, stream>>>(item_fea, mlp_w,
                                                                      mlp_b, f_ego);

    if (use_csr) {
        // ---- build CSR (amortized over 4 layers) ----
        hipMemsetAsync(row_cnt, 0, kN * sizeof(int), stream);
        hist_k<<<(kNnz + 255) / 256, 256, 0, stream>>>(adj_rows, row_cnt);
        scan1_k<<<kNB, 256, 0, stream>>>(row_cnt, row_ptr, blk_sum);
        scan2_k<<<1, 256, 0, stream>>>(blk_sum, blk_off);
        scan3_k<<<kNB, 256, 0, stream>>>(row_ptr, row_fill, blk_off);
        scatter_k<<<(kNnz + 255) / 256, 256, 0, stream>>>(adj_rows, adj_cols, adj_vals,
                                                          row_fill, csr);

        norm_init_csr_k<<<(kN + 3) / 4, 256, 0, stream>>>(f_ego, f_nrm, acc);

        // ---- 4 fused layers: ego -> xa -> xb -> xa -> xb ----
        const float* xin = f_ego;
        float* xout = f_xa;
        for (int l = 0; l < 4; ++l) {
            layer_k<<<(kN + 3) / 4, 256, 0, stream>>>(row_ptr, csr, f_ego, f_nrm,
                                                      xin, xout, acc);
            xin  = xout;
            xout = (xout == f_xa) ? f_xb : f_xa;
        }
    } else {
        // ---- fallback: atomic path ----
        float* f_x = f_xa;
        float* f_y = f_xb;
        norm_init_full_k<<<(kN + 3) / 4, 256, 0, stream>>>(f_ego, f_nrm, f_x, acc);
        for (int l = 0; l < 4; ++l) {
            hipMemsetAsync(f_y, 0, NE * sizeof(float), stream);
            spmm_k<<<(int)(((long long)kNnz * 64 + 255) / 256), 256, 0, stream>>>(
                adj_rows, adj_cols, adj_vals, f_x, f_y);
            weight_k<<<(kN + 3) / 4, 256, 0, stream>>>(f_ego, f_nrm, f_y, f_x, acc);
        }
    }
}

// Round 5
// 1121.792 us; speedup vs baseline: 2.4181x; 1.0798x over previous
//
#include <hip/hip_runtime.h>

constexpr int kNUser = 100000;
constexpr int kNItem = 50000;
constexpr int kN     = 150000;
constexpr int kEmb   = 64;
constexpr int kFeat  = 384;
constexpr int kNnz   = 2400000;
constexpr float kEps = 1e-8f;

constexpr int kChunk = 1024;                       // elements per scan block
constexpr int kNB    = (kN + kChunk - 1) / kChunk; // 147 scan blocks

// ================= shared init kernels =================

__global__ void prompt_sum_k(const float* __restrict__ p, float* __restrict__ out) {
    int d = threadIdx.x;  // 64 threads
    float s = 0.f;
#pragma unroll
    for (int i = 0; i < 8; ++i) s += p[i * kEmb + d];
    out[d] = s;
}

__global__ void user_ego_k(const float* __restrict__ uf, const float* __restrict__ ps,
                           float* __restrict__ ego) {
    int i = blockIdx.x * blockDim.x + threadIdx.x;
    if (i >= kNUser * kEmb) return;
    ego[i] = uf[i] + ps[i & 63];
}

// ---- item MLP: 16 rows per wave, lane = out col; w chunk in registers ----
// __launch_bounds__(256,2): VGPR cap 256 so acc[16]+wreg[32] live set (~80 VGPR)
// does NOT spill (R4: default 64-VGPR target spilled ~100MB to scratch -> 340us).
constexpr int kRW = 16;
__global__ __launch_bounds__(256, 2)
void item_ego_k(const float* __restrict__ itf, const float* __restrict__ w,
                const float* __restrict__ b, float* __restrict__ ego) {
    int wid  = threadIdx.x >> 6;
    int lane = threadIdx.x & 63;
    int r0   = (blockIdx.x * 4 + wid) * kRW;
    if (r0 >= kNItem) return;
    float acc[kRW];
#pragma unroll
    for (int r = 0; r < kRW; ++r) acc[r] = 0.f;

    for (int kc = 0; kc < kFeat; kc += 32) {
        float wreg[32];
#pragma unroll
        for (int k = 0; k < 32; ++k) wreg[k] = w[(kc + k) * kEmb + lane];  // coalesced
#pragma unroll
        for (int r = 0; r < kRW; ++r) {
            const float4* ar = (const float4*)(itf + (size_t)(r0 + r) * kFeat + kc);
#pragma unroll
            for (int q = 0; q < 8; ++q) {            // wave-uniform broadcast loads
                float4 a = ar[q];
                acc[r] = fmaf(a.x, wreg[q * 4 + 0], acc[r]);
                acc[r] = fmaf(a.y, wreg[q * 4 + 1], acc[r]);
                acc[r] = fmaf(a.z, wreg[q * 4 + 2], acc[r]);
                acc[r] = fmaf(a.w, wreg[q * 4 + 3], acc[r]);
            }
        }
    }
    float bv = b[lane];
#pragma unroll
    for (int r = 0; r < kRW; ++r) {
        if (r0 + r < kNItem)
            ego[(size_t)(kNUser + r0 + r) * kEmb + lane] = tanhf(acc[r] + bv);
    }
}

// nrm + acc init (CSR path: layer 0 reads ego directly, no x copy needed)
__global__ void norm_init_csr_k(const float* __restrict__ ego, float* __restrict__ nrm,
                                float* __restrict__ acc) {
    int wid  = threadIdx.x >> 6;
    int lane = threadIdx.x & 63;
    int row  = blockIdx.x * 4 + wid;
    if (row >= kN) return;
    size_t idx = (size_t)row * kEmb + lane;
    float e = ego[idx];
    acc[idx] = e;
    float s = e * e;
#pragma unroll
    for (int o = 32; o >= 1; o >>= 1) s += __shfl_xor(s, o, 64);
    if (lane == 0) nrm[row] = sqrtf(s);
}

// ================= CSR build =================

__global__ void hist_k(const int* __restrict__ rows, int* __restrict__ cnt) {
    int e = blockIdx.x * blockDim.x + threadIdx.x;
    if (e < kNnz) atomicAdd(&cnt[rows[e]], 1);
}

__global__ void scan1_k(const int* __restrict__ cnt, int* __restrict__ excl_out,
                        int* __restrict__ blk_sum) {
    __shared__ int sd[256];
    int b = blockIdx.x, t = threadIdx.x;
    int base = b * kChunk + t * 4;
    int c0 = (base + 0 < kN) ? cnt[base + 0] : 0;
    int c1 = (base + 1 < kN) ? cnt[base + 1] : 0;
    int c2 = (base + 2 < kN) ? cnt[base + 2] : 0;
    int c3 = (base + 3 < kN) ? cnt[base + 3] : 0;
    int tsum = c0 + c1 + c2 + c3;
    sd[t] = tsum;
    __syncthreads();
#pragma unroll
    for (int off = 1; off < 256; off <<= 1) {
        int v = (t >= off) ? sd[t - off] : 0;
        __syncthreads();
        sd[t] += v;
        __syncthreads();
    }
    int excl = sd[t] - tsum;
    if (t == 255) blk_sum[b] = sd[255];
    int run = excl;
    if (base + 0 < kN) { excl_out[base + 0] = run; run += c0; }
    if (base + 1 < kN) { excl_out[base + 1] = run; run += c1; }
    if (base + 2 < kN) { excl_out[base + 2] = run; run += c2; }
    if (base + 3 < kN) { excl_out[base + 3] = run; run += c3; }
}

__global__ void scan2_k(const int* __restrict__ blk_sum, int* __restrict__ blk_off) {
    __shared__ int sd[256];
    int t = threadIdx.x;
    int v = (t < kNB) ? blk_sum[t] : 0;
    sd[t] = v;
    __syncthreads();
#pragma unroll
    for (int off = 1; off < 256; off <<= 1) {
        int u = (t >= off) ? sd[t - off] : 0;
        __syncthreads();
        sd[t] += u;
        __syncthreads();
    }
    if (t < kNB) blk_off[t] = sd[t] - v;
}

__global__ void scan3_k(int* __restrict__ rp, int* __restrict__ rf,
                        const int* __restrict__ blk_off) {
    int b = blockIdx.x, t = threadIdx.x;
    int base = b * kChunk + t * 4;
    int o = blk_off[b];
#pragma unroll
    for (int k = 0; k < 4; ++k) {
        int i = base + k;
        if (i < kN) { int v = rp[i] + o; rp[i] = v; rf[i] = v; }
    }
    if (b == 0 && t == 0) rp[kN] = kNnz;
}

__global__ void scatter_k(const int* __restrict__ rows, const int* __restrict__ cols,
                          const float* __restrict__ vals, int* __restrict__ rf,
                          int2* __restrict__ csr) {
    int e = blockIdx.x * blockDim.x + threadIdx.x;
    if (e >= kNnz) return;
    int r = rows[e];
    int pos = atomicAdd(&rf[r], 1);
    csr[pos] = make_int2(cols[e], __float_as_int(vals[e]));
}

// ============ fused layer: pull-SpMM + cosine reweight + acc ============
// one wave per row; lane = embedding dim; gather unrolled x8 for latency hiding
__global__ void layer_k(const int* __restrict__ rp, const int2* __restrict__ csr,
                        const float* __restrict__ ego, const float* __restrict__ nrm,
                        const float* __restrict__ xin, float* __restrict__ xout,
                        float* __restrict__ acc) {
    int wid  = threadIdx.x >> 6;
    int lane = threadIdx.x & 63;
    int row  = blockIdx.x * 4 + wid;
    if (row >= kN) return;
    int p0 = rp[row];
    int p1 = rp[row + 1];
    float s = 0.f;
    int j = p0;
    for (; j + 8 <= p1; j += 8) {
        int2 e[8];
        float a[8];
#pragma unroll
        for (int q = 0; q < 8; ++q) e[q] = csr[j + q];
#pragma unroll
        for (int q = 0; q < 8; ++q) a[q] = xin[(size_t)e[q].x * kEmb + lane];
#pragma unroll
        for (int q = 0; q < 8; ++q) s = fmaf(__int_as_float(e[q].y), a[q], s);
    }
    for (; j + 4 <= p1; j += 4) {
        int2 e0 = csr[j], e1 = csr[j + 1], e2 = csr[j + 2], e3 = csr[j + 3];
        float a0 = xin[(size_t)e0.x * kEmb + lane];
        float a1 = xin[(size_t)e1.x * kEmb + lane];
        float a2 = xin[(size_t)e2.x * kEmb + lane];
        float a3 = xin[(size_t)e3.x * kEmb + lane];
        s = fmaf(__int_as_float(e0.y), a0, s);
        s = fmaf(__int_as_float(e1.y), a1, s);
        s = fmaf(__int_as_float(e2.y), a2, s);
        s = fmaf(__int_as_float(e3.y), a3, s);
    }
    for (; j < p1; ++j) {
        int2 e = csr[j];
        s = fmaf(__int_as_float(e.y), xin[(size_t)e.x * kEmb + lane], s);
    }
    size_t idx = (size_t)row * kEmb + lane;
    float ev = ego[idx];
    float d = s * ev;
    float n = s * s;
#pragma unroll
    for (int o = 32; o >= 1; o >>= 1) {
        d += __shfl_xor(d, o, 64);
        n += __shfl_xor(n, o, 64);
    }
    float w  = d / fmaxf(sqrtf(n) * nrm[row], kEps);
    float xw = w * s;
    xout[idx] = xw;
    acc[idx] += xw;
}

// ================= fallback (atomic) kernels =================

__global__ void norm_init_full_k(const float* __restrict__ ego, float* __restrict__ nrm,
                                 float* __restrict__ x, float* __restrict__ acc) {
    int wid  = threadIdx.x >> 6;
    int lane = threadIdx.x & 63;
    int row  = blockIdx.x * 4 + wid;
    if (row >= kN) return;
    size_t idx = (size_t)row * kEmb + lane;
    float e = ego[idx];
    x[idx]   = e;
    acc[idx] = e;
    float s = e * e;
#pragma unroll
    for (int o = 32; o >= 1; o >>= 1) s += __shfl_xor(s, o, 64);
    if (lane == 0) nrm[row] = sqrtf(s);
}

__global__ void spmm_k(const int* __restrict__ rows, const int* __restrict__ cols,
                       const float* __restrict__ vals, const float* __restrict__ x,
                       float* __restrict__ y) {
    long long t = (long long)blockIdx.x * blockDim.x + threadIdx.x;
    int e = (int)(t >> 6);
    if (e >= kNnz) return;
    int lane = threadIdx.x & 63;
    atomicAdd(y + (size_t)rows[e] * kEmb + lane, vals[e] * x[(size_t)cols[e] * kEmb + lane]);
}

__global__ void weight_k(const float* __restrict__ ego, const float* __restrict__ nrm,
                         const float* __restrict__ y, float* __restrict__ x,
                         float* __restrict__ acc) {
    int wid  = threadIdx.x >> 6;
    int lane = threadIdx.x & 63;
    int row  = blockIdx.x * 4 + wid;
    if (row >= kN) return;
    size_t idx = (size_t)row * kEmb + lane;
    float yv = y[idx];
    float ev = ego[idx];
    float d = yv * ev;
    float n = yv * yv;
#pragma unroll
    for (int o = 32; o >= 1; o >>= 1) {
        d += __shfl_xor(d, o, 64);
        n += __shfl_xor(n, o, 64);
    }
    float w  = d / fmaxf(sqrtf(n) * nrm[row], kEps);
    float xw = w * yv;
    x[idx] = xw;
    acc[idx] += xw;
}

// ================= launch =================

extern "C" void kernel_launch(void* const* d_in, const int* in_sizes, int n_in,
                              void* d_out, int out_size, void* d_ws, size_t ws_size,
                              hipStream_t stream) {
    const float* user_fea = (const float*)d_in[0];
    const float* item_fea = (const float*)d_in[1];
    const float* prompt   = (const float*)d_in[2];
    const float* mlp_w    = (const float*)d_in[3];
    const float* mlp_b    = (const float*)d_in[4];
    const int*   adj_rows = (const int*)d_in[5];
    const int*   adj_cols = (const int*)d_in[6];
    const float* adj_vals = (const float*)d_in[7];
    float* acc = (float*)d_out;   // running layer sum accumulates in-place in d_out

    const size_t NE = (size_t)kN * kEmb;  // 9.6M
    float* ws = (float*)d_ws;

    // ---- CSR-path workspace layout (4-byte units) ----
    size_t off = 0;
    float* f_ego = ws + off; off += NE;
    float* f_xa  = ws + off; off += NE;
    float* f_xb  = ws + off; off += NE;
    float* f_nrm = ws + off; off += kN;
    float* f_ps  = ws + off; off += 64;
    int* row_cnt  = (int*)(ws + off); off += kN;
    int* row_ptr  = (int*)(ws + off); off += kN + 1;
    int* row_fill = (int*)(ws + off); off += kN;
    int* blk_sum  = (int*)(ws + off); off += kNB;
    int* blk_off  = (int*)(ws + off); off += kNB;
    off = (off + 1) & ~(size_t)1;                   // 8B-align csr
    int2* csr = (int2*)(ws + off); off += (size_t)kNnz * 2;
    const bool use_csr = ws_size >= off * 4;

    // ---- common init ----
    prompt_sum_k<<<1, 64, 0, stream>>>(prompt, f_ps);
    user_ego_k<<<(kNUser * kEmb + 255) / 256, 256, 0, stream>>>(user_fea, f_ps, f_ego);
    item_ego_k<<<(kNItem + 4 * kRW - 1) / (4 * kRW), 256, 0, stream>>>(item_fea, mlp_w,
                                                                      mlp_b, f_ego);

    if (use_csr) {
        // ---- build CSR (amortized over 4 layers) ----
        hipMemsetAsync(row_cnt, 0, kN * sizeof(int), stream);
        hist_k<<<(kNnz + 255) / 256, 256, 0, stream>>>(adj_rows, row_cnt);
        scan1_k<<<kNB, 256, 0, stream>>>(row_cnt, row_ptr, blk_sum);
        scan2_k<<<1, 256, 0, stream>>>(blk_sum, blk_off);
        scan3_k<<<kNB, 256, 0, stream>>>(row_ptr, row_fill, blk_off);
        scatter_k<<<(kNnz + 255) / 256, 256, 0, stream>>>(adj_rows, adj_cols, adj_vals,
                                                          row_fill, csr);

        norm_init_csr_k<<<(kN + 3) / 4, 256, 0, stream>>>(f_ego, f_nrm, acc);

        // ---- 4 fused layers: ego -> xa -> xb -> xa -> xb ----
        const float* xin = f_ego;
        float* xout = f_xa;
        for (int l = 0; l < 4; ++l) {
            layer_k<<<(kN + 3) / 4, 256, 0, stream>>>(row_ptr, csr, f_ego, f_nrm,
                                                      xin, xout, acc);
            xin  = xout;
            xout = (xout == f_xa) ? f_xb : f_xa;
        }
    } else {
        // ---- fallback: atomic path ----
        float* f_x = f_xa;
        float* f_y = f_xb;
        norm_init_full_k<<<(kN + 3) / 4, 256, 0, stream>>>(f_ego, f_nrm, f_x, acc);
        for (int l = 0; l < 4; ++l) {
            hipMemsetAsync(f_y, 0, NE * sizeof(float), stream);
            spmm_k<<<(int)(((long long)kNnz * 64 + 255) / 256), 256, 0, stream>>>(
                adj_rows, adj_cols, adj_vals, f_x, f_y);
            weight_k<<<(kN + 3) / 4, 256, 0, stream>>>(f_ego, f_nrm, f_y, f_x, acc);
        }
    }
}

// Round 6
// 1017.207 us; speedup vs baseline: 2.6667x; 1.1028x over previous
//
#include <hip/hip_runtime.h>

constexpr int kNUser = 100000;
constexpr int kNItem = 50000;
constexpr int kN     = 150000;
constexpr int kEmb   = 64;
constexpr int kFeat  = 384;
constexpr int kNnz   = 2400000;
constexpr float kEps = 1e-8f;

constexpr int kChunk = 1024;                       // elements per scan block
constexpr int kNB    = (kN + kChunk - 1) / kChunk; // 147 scan blocks

// ================= shared init kernels =================

__global__ void prompt_sum_k(const float* __restrict__ p, float* __restrict__ out) {
    int d = threadIdx.x;  // 64 threads
    float s = 0.f;
#pragma unroll
    for (int i = 0; i < 8; ++i) s += p[i * kEmb + d];
    out[d] = s;
}

__global__ void user_ego_k(const float* __restrict__ uf, const float* __restrict__ ps,
                           float* __restrict__ ego) {
    int i = blockIdx.x * blockDim.x + threadIdx.x;
    if (i >= kNUser * kEmb) return;
    ego[i] = uf[i] + ps[i & 63];
}

// ---- item MLP: block = 64 rows; A staged through LDS (coalesced), compute
// reads A as wave-uniform ds_read_b128 broadcasts. R5 post-mortem: the
// 1536 wave-uniform global float4 loads/wave were VMEM-issue/latency bound
// (259us @ VALUBusy 17%). LDS staging cuts per-wave VMEM ~1920 -> ~400.
constexpr int kRW      = 16;   // rows per wave
constexpr int kRowsBlk = 64;   // rows per block (4 waves)
constexpr int kKc      = 32;   // K-chunk

__global__ __launch_bounds__(256, 2)
void item_ego_k(const float* __restrict__ itf, const float* __restrict__ w,
                const float* __restrict__ b, float* __restrict__ ego) {
    __shared__ float lds_a[kRowsBlk * kKc];  // 8 KB
    int t      = threadIdx.x;
    int wid    = t >> 6;
    int lane   = t & 63;
    int blk_r0 = blockIdx.x * kRowsBlk;

    float acc[kRW];
#pragma unroll
    for (int r = 0; r < kRW; ++r) acc[r] = 0.f;

    int srow = t >> 3;             // 0..31
    int scol = (t & 7) * 4;        // 0,4,..,28

    for (int kc = 0; kc < kFeat; kc += kKc) {
        __syncthreads();  // previous-chunk LDS reads done
        // ---- stage A tile: 64 rows x 32 k = 2048 floats, 2 float4/thread ----
        {
            const float4 z = make_float4(0.f, 0.f, 0.f, 0.f);
            int gr0 = blk_r0 + srow;
            int gr1 = gr0 + 32;
            float4 v0 = (gr0 < kNItem)
                ? *(const float4*)(itf + (size_t)gr0 * kFeat + kc + scol) : z;
            float4 v1 = (gr1 < kNItem)
                ? *(const float4*)(itf + (size_t)gr1 * kFeat + kc + scol) : z;
            *(float4*)(lds_a + srow * kKc + scol)        = v0;
            *(float4*)(lds_a + (srow + 32) * kKc + scol) = v1;
        }
        // ---- W chunk into registers (coalesced, independent of LDS) ----
        float wreg[kKc];
#pragma unroll
        for (int k = 0; k < kKc; ++k) wreg[k] = w[(kc + k) * kEmb + lane];
        __syncthreads();  // staging visible
        // ---- compute: wave-uniform LDS broadcasts ----
#pragma unroll
        for (int r = 0; r < kRW; ++r) {
            const float4* av = (const float4*)(lds_a + (wid * kRW + r) * kKc);
#pragma unroll
            for (int q = 0; q < 8; ++q) {
                float4 a = av[q];
                acc[r] = fmaf(a.x, wreg[q * 4 + 0], acc[r]);
                acc[r] = fmaf(a.y, wreg[q * 4 + 1], acc[r]);
                acc[r] = fmaf(a.z, wreg[q * 4 + 2], acc[r]);
                acc[r] = fmaf(a.w, wreg[q * 4 + 3], acc[r]);
            }
        }
    }
    float bv = b[lane];
#pragma unroll
    for (int r = 0; r < kRW; ++r) {
        int row = blk_r0 + wid * kRW + r;
        if (row < kNItem)
            ego[(size_t)(kNUser + row) * kEmb + lane] = tanhf(acc[r] + bv);
    }
}

// nrm + acc init (CSR path: layer 0 reads ego directly, no x copy needed)
__global__ void norm_init_csr_k(const float* __restrict__ ego, float* __restrict__ nrm,
                                float* __restrict__ acc) {
    int wid  = threadIdx.x >> 6;
    int lane = threadIdx.x & 63;
    int row  = blockIdx.x * 4 + wid;
    if (row >= kN) return;
    size_t idx = (size_t)row * kEmb + lane;
    float e = ego[idx];
    acc[idx] = e;
    float s = e * e;
#pragma unroll
    for (int o = 32; o >= 1; o >>= 1) s += __shfl_xor(s, o, 64);
    if (lane == 0) nrm[row] = sqrtf(s);
}

// ================= CSR build =================

__global__ void hist_k(const int* __restrict__ rows, int* __restrict__ cnt) {
    int e = blockIdx.x * blockDim.x + threadIdx.x;
    if (e < kNnz) atomicAdd(&cnt[rows[e]], 1);
}

__global__ void scan1_k(const int* __restrict__ cnt, int* __restrict__ excl_out,
                        int* __restrict__ blk_sum) {
    __shared__ int sd[256];
    int b = blockIdx.x, t = threadIdx.x;
    int base = b * kChunk + t * 4;
    int c0 = (base + 0 < kN) ? cnt[base + 0] : 0;
    int c1 = (base + 1 < kN) ? cnt[base + 1] : 0;
    int c2 = (base + 2 < kN) ? cnt[base + 2] : 0;
    int c3 = (base + 3 < kN) ? cnt[base + 3] : 0;
    int tsum = c0 + c1 + c2 + c3;
    sd[t] = tsum;
    __syncthreads();
#pragma unroll
    for (int off = 1; off < 256; off <<= 1) {
        int v = (t >= off) ? sd[t - off] : 0;
        __syncthreads();
        sd[t] += v;
        __syncthreads();
    }
    int excl = sd[t] - tsum;
    if (t == 255) blk_sum[b] = sd[255];
    int run = excl;
    if (base + 0 < kN) { excl_out[base + 0] = run; run += c0; }
    if (base + 1 < kN) { excl_out[base + 1] = run; run += c1; }
    if (base + 2 < kN) { excl_out[base + 2] = run; run += c2; }
    if (base + 3 < kN) { excl_out[base + 3] = run; run += c3; }
}

__global__ void scan2_k(const int* __restrict__ blk_sum, int* __restrict__ blk_off) {
    __shared__ int sd[256];
    int t = threadIdx.x;
    int v = (t < kNB) ? blk_sum[t] : 0;
    sd[t] = v;
    __syncthreads();
#pragma unroll
    for (int off = 1; off < 256; off <<= 1) {
        int u = (t >= off) ? sd[t - off] : 0;
        __syncthreads();
        sd[t] += u;
        __syncthreads();
    }
    if (t < kNB) blk_off[t] = sd[t] - v;
}

__global__ void scan3_k(int* __restrict__ rp, int* __restrict__ rf,
                        const int* __restrict__ blk_off) {
    int b = blockIdx.x, t = threadIdx.x;
    int base = b * kChunk + t * 4;
    int o = blk_off[b];
#pragma unroll
    for (int k = 0; k < 4; ++k) {
        int i = base + k;
        if (i < kN) { int v = rp[i] + o; rp[i] = v; rf[i] = v; }
    }
    if (b == 0 && t == 0) rp[kN] = kNnz;
}

__global__ void scatter_k(const int* __restrict__ rows, const int* __restrict__ cols,
                          const float* __restrict__ vals, int* __restrict__ rf,
                          int2* __restrict__ csr) {
    int e = blockIdx.x * blockDim.x + threadIdx.x;
    if (e >= kNnz) return;
    int r = rows[e];
    int pos = atomicAdd(&rf[r], 1);
    csr[pos] = make_int2(cols[e], __float_as_int(vals[e]));
}

// ============ fused layer: pull-SpMM + cosine reweight + acc ============
// one wave per row; lane = embedding dim; gather unrolled x8 for latency hiding
__global__ void layer_k(const int* __restrict__ rp, const int2* __restrict__ csr,
                        const float* __restrict__ ego, const float* __restrict__ nrm,
                        const float* __restrict__ xin, float* __restrict__ xout,
                        float* __restrict__ acc) {
    int wid  = threadIdx.x >> 6;
    int lane = threadIdx.x & 63;
    int row  = blockIdx.x * 4 + wid;
    if (row >= kN) return;
    int p0 = rp[row];
    int p1 = rp[row + 1];
    float s = 0.f;
    int j = p0;
    for (; j + 8 <= p1; j += 8) {
        int2 e[8];
        float a[8];
#pragma unroll
        for (int q = 0; q < 8; ++q) e[q] = csr[j + q];
#pragma unroll
        for (int q = 0; q < 8; ++q) a[q] = xin[(size_t)e[q].x * kEmb + lane];
#pragma unroll
        for (int q = 0; q < 8; ++q) s = fmaf(__int_as_float(e[q].y), a[q], s);
    }
    for (; j + 4 <= p1; j += 4) {
        int2 e0 = csr[j], e1 = csr[j + 1], e2 = csr[j + 2], e3 = csr[j + 3];
        float a0 = xin[(size_t)e0.x * kEmb + lane];
        float a1 = xin[(size_t)e1.x * kEmb + lane];
        float a2 = xin[(size_t)e2.x * kEmb + lane];
        float a3 = xin[(size_t)e3.x * kEmb + lane];
        s = fmaf(__int_as_float(e0.y), a0, s);
        s = fmaf(__int_as_float(e1.y), a1, s);
        s = fmaf(__int_as_float(e2.y), a2, s);
        s = fmaf(__int_as_float(e3.y), a3, s);
    }
    for (; j < p1; ++j) {
        int2 e = csr[j];
        s = fmaf(__int_as_float(e.y), xin[(size_t)e.x * kEmb + lane], s);
    }
    size_t idx = (size_t)row * kEmb + lane;
    float ev = ego[idx];
    float d = s * ev;
    float n = s * s;
#pragma unroll
    for (int o = 32; o >= 1; o >>= 1) {
        d += __shfl_xor(d, o, 64);
        n += __shfl_xor(n, o, 64);
    }
    float w  = d / fmaxf(sqrtf(n) * nrm[row], kEps);
    float xw = w * s;
    xout[idx] = xw;
    acc[idx] += xw;
}

// ================= fallback (atomic) kernels =================

__global__ void norm_init_full_k(const float* __restrict__ ego, float* __restrict__ nrm,
                                 float* __restrict__ x, float* __restrict__ acc) {
    int wid  = threadIdx.x >> 6;
    int lane = threadIdx.x & 63;
    int row  = blockIdx.x * 4 + wid;
    if (row >= kN) return;
    size_t idx = (size_t)row * kEmb + lane;
    float e = ego[idx];
    x[idx]   = e;
    acc[idx] = e;
    float s = e * e;
#pragma unroll
    for (int o = 32; o >= 1; o >>= 1) s += __shfl_xor(s, o, 64);
    if (lane == 0) nrm[row] = sqrtf(s);
}

__global__ void spmm_k(const int* __restrict__ rows, const int* __restrict__ cols,
                       const float* __restrict__ vals, const float* __restrict__ x,
                       float* __restrict__ y) {
    long long t = (long long)blockIdx.x * blockDim.x + threadIdx.x;
    int e = (int)(t >> 6);
    if (e >= kNnz) return;
    int lane = threadIdx.x & 63;
    atomicAdd(y + (size_t)rows[e] * kEmb + lane, vals[e] * x[(size_t)cols[e] * kEmb + lane]);
}

__global__ void weight_k(const float* __restrict__ ego, const float* __restrict__ nrm,
                         const float* __restrict__ y, float* __restrict__ x,
                         float* __restrict__ acc) {
    int wid  = threadIdx.x >> 6;
    int lane = threadIdx.x & 63;
    int row  = blockIdx.x * 4 + wid;
    if (row >= kN) return;
    size_t idx = (size_t)row * kEmb + lane;
    float yv = y[idx];
    float ev = ego[idx];
    float d = yv * ev;
    float n = yv * yv;
#pragma unroll
    for (int o = 32; o >= 1; o >>= 1) {
        d += __shfl_xor(d, o, 64);
        n += __shfl_xor(n, o, 64);
    }
    float w  = d / fmaxf(sqrtf(n) * nrm[row], kEps);
    float xw = w * yv;
    x[idx] = xw;
    acc[idx] += xw;
}

// ================= launch =================

extern "C" void kernel_launch(void* const* d_in, const int* in_sizes, int n_in,
                              void* d_out, int out_size, void* d_ws, size_t ws_size,
                              hipStream_t stream) {
    const float* user_fea = (const float*)d_in[0];
    const float* item_fea = (const float*)d_in[1];
    const float* prompt   = (const float*)d_in[2];
    const float* mlp_w    = (const float*)d_in[3];
    const float* mlp_b    = (const float*)d_in[4];
    const int*   adj_rows = (const int*)d_in[5];
    const int*   adj_cols = (const int*)d_in[6];
    const float* adj_vals = (const float*)d_in[7];
    float* acc = (float*)d_out;   // running layer sum accumulates in-place in d_out

    const size_t NE = (size_t)kN * kEmb;  // 9.6M
    float* ws = (float*)d_ws;

    // ---- CSR-path workspace layout (4-byte units) ----
    size_t off = 0;
    float* f_ego = ws + off; off += NE;
    float* f_xa  = ws + off; off += NE;
    float* f_xb  = ws + off; off += NE;
    float* f_nrm = ws + off; off += kN;
    float* f_ps  = ws + off; off += 64;
    int* row_cnt  = (int*)(ws + off); off += kN;
    int* row_ptr  = (int*)(ws + off); off += kN + 1;
    int* row_fill = (int*)(ws + off); off += kN;
    int* blk_sum  = (int*)(ws + off); off += kNB;
    int* blk_off  = (int*)(ws + off); off += kNB;
    off = (off + 1) & ~(size_t)1;                   // 8B-align csr
    int2* csr = (int2*)(ws + off); off += (size_t)kNnz * 2;
    const bool use_csr = ws_size >= off * 4;

    // ---- common init ----
    prompt_sum_k<<<1, 64, 0, stream>>>(prompt, f_ps);
    user_ego_k<<<(kNUser * kEmb + 255) / 256, 256, 0, stream>>>(user_fea, f_ps, f_ego);
    item_ego_k<<<(kNItem + kRowsBlk - 1) / kRowsBlk, 256, 0, stream>>>(item_fea, mlp_w,
                                                                      mlp_b, f_ego);

    if (use_csr) {
        // ---- build CSR (amortized over 4 layers) ----
        hipMemsetAsync(row_cnt, 0, kN * sizeof(int), stream);
        hist_k<<<(kNnz + 255) / 256, 256, 0, stream>>>(adj_rows, row_cnt);
        scan1_k<<<kNB, 256, 0, stream>>>(row_cnt, row_ptr, blk_sum);
        scan2_k<<<1, 256, 0, stream>>>(blk_sum, blk_off);
        scan3_k<<<kNB, 256, 0, stream>>>(row_ptr, row_fill, blk_off);
        scatter_k<<<(kNnz + 255) / 256, 256, 0, stream>>>(adj_rows, adj_cols, adj_vals,
                                                          row_fill, csr);

        norm_init_csr_k<<<(kN + 3) / 4, 256, 0, stream>>>(f_ego, f_nrm, acc);

        // ---- 4 fused layers: ego -> xa -> xb -> xa -> xb ----
        const float* xin = f_ego;
        float* xout = f_xa;
        for (int l = 0; l < 4; ++l) {
            layer_k<<<(kN + 3) / 4, 256, 0, stream>>>(row_ptr, csr, f_ego, f_nrm,
                                                      xin, xout, acc);
            xin  = xout;
            xout = (xout == f_xa) ? f_xb : f_xa;
        }
    } else {
        // ---- fallback: atomic path ----
        float* f_x = f_xa;
        float* f_y = f_xb;
        norm_init_full_k<<<(kN + 3) / 4, 256, 0, stream>>>(f_ego, f_nrm, f_x, acc);
        for (int l = 0; l < 4; ++l) {
            hipMemsetAsync(f_y, 0, NE * sizeof(float), stream);
            spmm_k<<<(int)(((long long)kNnz * 64 + 255) / 256), 256, 0, stream>>>(
                adj_rows, adj_cols, adj_vals, f_x, f_y);
            weight_k<<<(kN + 3) / 4, 256, 0, stream>>>(f_ego, f_nrm, f_y, f_x, acc);
        }
    }
}